// Round 7
// baseline (174.815 us; speedup 1.0000x reference)
//
#include <hip/hip_runtime.h>

// SNNLinear, exact-trajectory i8-digit MFMA. Round 25 = register diet v2
// (plane-sequential B) -> real 3 waves/SIMD.
// R24 post-mortem: (64,3) still spilled (VGPR_Count 84, WRITE 43 MB) --
// 11 live fragments (44 regs) + addresses on top of acc 112 overran the
// ~170 cap. R22 showed prefetch at 2 waves/SIMD is flat -> the lever is
// occupancy, not intra-wave order.
// R25 diet: GEMM-loop high-water = acc 112 + af 28 + B ping-pong 8 +
// ~8 addr ~= 156 <= 170:
//   - B processed plane-at-a-time: named b0/b1 ping-pong (static, never
//     runtime-indexed), plane p+1 prefetched during plane p's 7 MFMAs.
//     Bt kt-chunk is plane-contiguous: one base, imm offsets 0..3072.
//   - A kt-chunk contiguous (R24 layout): two bases (ak, ak+4096) so all
//     7 loads are base+13-bit-imm, zero per-fragment address regs.
//   - LDS 12.8 KB -> exactly 12 blocks/CU; grid/mapping/scan = R21.
// Math identical to R19..R24 (all passed): exact 0/1 A, 4 balanced
// base-256 i8 planes of round(W*2^28), mfma_i32_16x16x64_i8 exact,
// i64 Horner -> exact f64 du -> f64 scan verbatim.
// Outputs: ss[100,64,1024] | mem_out[64,1024] | hat_s[64,1024]
// ws: [0, 7.34M) A8 (b-major, kt-contiguous) ; [7.34M, 11.53M) Bt (4 planes)

typedef __attribute__((ext_vector_type(4))) int int4v;

#define T_STEPS 100
#define T_PAD   112
#define BO      65536
#define K_DIM   1024
#define A8_OFF  0
#define BT_OFF  7340032      // 64*112*1024

// ---- prepass (R24 verbatim): spikes -> A8 (b-major, kt-contiguous tiles);
//               W -> Bt 4 balanced base-256 i8 planes ----
__global__ __launch_bounds__(256)
void prepass(const float* __restrict__ S, const float* __restrict__ W,
             signed char* __restrict__ A8, signed char* __restrict__ Bt) {
    const int wave = blockIdx.x * 4 + (threadIdx.x >> 6);  // 0..8191
    const int lane = threadIdx.x & 63;
    const int r16 = lane & 15, quad = lane >> 4;

    if (wave < 7168) {
        // A tile: wave = b*112 + jt*16 + k64 ; rows t = jt*16 + r16
        const int b   = wave / 112;
        const int rem = wave - b * 112;
        const int jt  = rem >> 4, k64 = rem & 15;
        const int t   = jt * 16 + r16;
        union { signed char c[16]; int4v v; } u;
        if (t < T_STEPS) {
            const float* sp = S + ((size_t)t * 64 + b) * K_DIM + k64 * 64 + quad * 16;
            const float4 s0 = *(const float4*)(sp);
            const float4 s1 = *(const float4*)(sp + 4);
            const float4 s2 = *(const float4*)(sp + 8);
            const float4 s3 = *(const float4*)(sp + 12);
            const float sv[16] = {s0.x,s0.y,s0.z,s0.w, s1.x,s1.y,s1.z,s1.w,
                                  s2.x,s2.y,s2.z,s2.w, s3.x,s3.y,s3.z,s3.w};
#pragma unroll
            for (int e = 0; e < 16; ++e) u.c[e] = (signed char)sv[e];  // exact 0/1
        } else {
#pragma unroll
            for (int e = 0; e < 16; ++e) u.c[e] = 0;                   // t-pad
        }
        // kt-contiguous chunk index: k64*7 + jt
        *(int4v*)(A8 + ((size_t)(b * 112 + k64 * 7 + jt)) * 1024 + lane * 16) = u.v;
    } else {
        const int t2 = wave - 7168;                 // 0..1023
        const int n16 = t2 >> 4, k64 = t2 & 15;
        const int n = n16 * 16 + r16;
        const float* wp = W + (size_t)n * K_DIM + k64 * 64 + quad * 16;
        const float4 w0 = *(const float4*)(wp);
        const float4 w1 = *(const float4*)(wp + 4);
        const float4 w2 = *(const float4*)(wp + 8);
        const float4 w3 = *(const float4*)(wp + 12);
        const float wv[16] = {w0.x,w0.y,w0.z,w0.w, w1.x,w1.y,w1.z,w1.w,
                              w2.x,w2.y,w2.z,w2.w, w3.x,w3.y,w3.z,w3.w};
        union { signed char c[16]; int4v v; } u[4];
#pragma unroll
        for (int e = 0; e < 16; ++e) {
            long long q = llrint((double)wv[e] * 0x1p28);   // |q| < 2^31
#pragma unroll
            for (int p = 0; p < 3; ++p) {
                const int d = (int)(((q + 128) & 255) - 128);  // [-128,127]
                u[p].c[e] = (signed char)d;
                q = (q - d) >> 8;                              // exact
            }
            u[3].c[e] = (signed char)q;                        // |d3| <= ~88
        }
        signed char* base = Bt + (size_t)(n16 * 16 + k64) * 4 * 1024 + lane * 16;
#pragma unroll
        for (int p = 0; p < 4; ++p)
            *(int4v*)(base + (size_t)p * 1024) = u[p].v;
    }
}

// 7 MFMAs of one plane P against B-register BREG
#define PLANE_MFMA(P, BREG)                                                   \
    {                                                                         \
        _Pragma("unroll")                                                     \
        for (int i = 0; i < 7; ++i)                                           \
            acc[i][P] = __builtin_amdgcn_mfma_i32_16x16x64_i8(                \
                af[i], BREG, acc[i][P], 0, 0, 0);                             \
    }

// ---- fused GEMM + scan, one wave per block, 3 waves/SIMD. ----
__global__ __launch_bounds__(64, 3)
void gemm_scan(const signed char* __restrict__ A8,
               const signed char* __restrict__ Bt,
               const float* __restrict__ bias,
               const float* __restrict__ mem0,
               float* __restrict__ out) {
    __shared__ double dulds[T_STEPS * 16];       // 12800 B -> 12 blocks/CU

    const int bid = blockIdx.x;                  // 0..4095
    const int ng  = bid >> 6;                    // n16 tile 0..63
    const int b   = bid & 63;                    // same-CU waves share b (A panel in L1)

    const int lane = threadIdx.x & 63;
    const int quad = lane >> 4, r16 = lane & 15;

    const signed char* abase = A8 + (size_t)b * T_PAD * 1024 + lane * 16;
    const signed char* bbase = Bt + (size_t)ng * 65536 + lane * 16;

    int4v acc[7][4] = {};

    for (int kt = 0; kt < 16; ++kt) {
        const signed char* ak  = abase + (size_t)kt * 7168;
        const signed char* ak2 = ak + 4096;
        const signed char* bk  = bbase + (size_t)kt * 4096;
        int4v af[7];
        // A fragments: base+imm only (offsets <= 3072)
        af[0] = *(const int4v*)(ak);
        af[1] = *(const int4v*)(ak + 1024);
        af[2] = *(const int4v*)(ak + 2048);
        af[3] = *(const int4v*)(ak + 3072);
        af[4] = *(const int4v*)(ak2);
        af[5] = *(const int4v*)(ak2 + 1024);
        af[6] = *(const int4v*)(ak2 + 2048);
        // plane-sequential B: static ping-pong b0/b1
        int4v b0 = *(const int4v*)(bk);
        int4v b1 = *(const int4v*)(bk + 1024);
        PLANE_MFMA(0, b0);
        b0 = *(const int4v*)(bk + 2048);
        PLANE_MFMA(1, b1);
        b1 = *(const int4v*)(bk + 3072);
        PLANE_MFMA(2, b0);
        PLANE_MFMA(3, b1);
    }

    // exact i64 Horner -> f64 du -> LDS transpose (row t, col r16)
    const double bd = (double)bias[ng * 16 + r16];
#pragma unroll
    for (int i = 0; i < 7; ++i)
#pragma unroll
        for (int e = 0; e < 4; ++e) {
            const int t = i * 16 + quad * 4 + e;
            if (t < T_STEPS) {
                long long v = (long long)acc[i][3][e];
                v = v * 256 + (long long)acc[i][2][e];
                v = v * 256 + (long long)acc[i][1][e];
                v = v * 256 + (long long)acc[i][0][e];   // exact, |v| < 2^42
                dulds[t * 16 + r16] = (double)v * 0x1p-28 + bd;
            }
        }
    __syncthreads();   // single wave: compiles to a waitcnt

    // membrane scan (R16 math verbatim, exact f64 du): 16 lanes, 16 columns.
    if (lane < 16) {
        const int bo = b * 1024 + ng * 16 + lane;
        double m = (double)mem0[bo];
        double cnt = 0.0;
        double d[4];
#pragma unroll
        for (int u = 0; u < 4; ++u) d[u] = dulds[u * 16 + lane];
        for (int g = 0; g < 25; ++g) {
            double dn[4];
            if (g + 1 < 25) {
#pragma unroll
                for (int u = 0; u < 4; ++u) dn[u] = dulds[((g + 1) * 4 + u) * 16 + lane];
            }
#pragma unroll
            for (int u = 0; u < 4; ++u) {
                m += d[u];
                const double s = (m > 15.0) ? 1.0 : 0.0;
                m = fmin(fmax(m, 0.0), 15.0);
                out[(size_t)(g * 4 + u) * BO + bo] = (float)s;
                cnt += s;
                m -= m * s;
            }
            if (g + 1 < 25) {
#pragma unroll
                for (int u = 0; u < 4; ++u) d[u] = dn[u];
            }
        }
        out[(size_t)T_STEPS * BO + bo] = (float)m;
        out[(size_t)(T_STEPS + 1) * BO + bo] = (float)(cnt * 0.01);
    }
}

extern "C" void kernel_launch(void* const* d_in, const int* in_sizes, int n_in,
                              void* d_out, int out_size, void* d_ws, size_t ws_size,
                              hipStream_t stream) {
    const float* spikes = (const float*)d_in[0];  // [100,64,1024]
    const float* mem    = (const float*)d_in[1];  // [64,1024]
    // d_in[2] = hat_spikes: dead in forward
    const float* W      = (const float*)d_in[3];  // [1024,1024]
    const float* b      = (const float*)d_in[4];  // [1024]
    float* out = (float*)d_out;
    signed char* A8 = (signed char*)d_ws + A8_OFF;
    signed char* Bt = (signed char*)d_ws + BT_OFF;

    prepass<<<dim3(2048), 256, 0, stream>>>(spikes, W, A8, Bt);
    gemm_scan<<<dim3(4096), 64, 0, stream>>>(A8, Bt, b, mem, out);
}

// Round 8
// 166.034 us; speedup vs baseline: 1.0529x; 1.0529x over previous
//
#include <hip/hip_runtime.h>

// SNNLinear, exact-trajectory i8-digit MFMA. Round 26 = PLANE-SPLIT waves
// (acc footprint halved -> 4 waves/SIMD).
// R24/R25 post-mortem: launch_bounds(64,3) spills ALWAYS -- the allocator
// splits the unified 170-reg budget ~84 VGPR / 86 AGPR and acc[7][4]=112
// doesn't fit the AGPR half -> acc spills in the MFMA loop (WRITE 160 MB).
// The binding constraint is TLP (2 aligned waves/SIMD can't hide ~500cy
// fragment latency vs 143cy MFMA/kt; every intra-wave reorder lands
// 43-52us). The register fat is the x4-plane accumulator.
// R26: block = 128 thr = 2 waves, SAME (b,ng) task; wave w computes
// planes {2w,2w+1}: acc[7][2]=56 regs, af 28, B 8 -> ~110 high-water
// -> launch_bounds(128,4) = 4 waves/SIMD, no allocator fight (AGPR
// section needs only 56). Total MFMA work unchanged (14/kt/wave).
// Exact combine: v = v0 + 2^16*v1, v_w = d(2w) + 256*d(2w+1) in i64;
// wave1 stages v1 in the 12.8KB LDS buffer (i64), barrier, wave0 merges
// -> exact f64 du -> scan verbatim. Waves/SIMD come from 4 different
// blocks -> decorrelated stalls. A-frag loads duplicated across the 2
// waves but L1-served (same lines, same CU).
// Math identical to R19..R25 (all passed): exact 0/1 A, 4 balanced
// base-256 i8 planes of round(W*2^28), mfma_i32_16x16x64_i8 exact,
// i64 Horner -> exact f64 du -> f64 scan verbatim.
// Outputs: ss[100,64,1024] | mem_out[64,1024] | hat_s[64,1024]
// ws: [0, 7.34M) A8 (b-major, kt-contiguous) ; [7.34M, 11.53M) Bt (4 planes)

typedef __attribute__((ext_vector_type(4))) int int4v;

#define T_STEPS 100
#define T_PAD   112
#define BO      65536
#define K_DIM   1024
#define A8_OFF  0
#define BT_OFF  7340032      // 64*112*1024

// ---- prepass (R24 verbatim): spikes -> A8 (b-major, kt-contiguous tiles);
//               W -> Bt 4 balanced base-256 i8 planes ----
__global__ __launch_bounds__(256)
void prepass(const float* __restrict__ S, const float* __restrict__ W,
             signed char* __restrict__ A8, signed char* __restrict__ Bt) {
    const int wave = blockIdx.x * 4 + (threadIdx.x >> 6);  // 0..8191
    const int lane = threadIdx.x & 63;
    const int r16 = lane & 15, quad = lane >> 4;

    if (wave < 7168) {
        // A tile: wave = b*112 + jt*16 + k64 ; rows t = jt*16 + r16
        const int b   = wave / 112;
        const int rem = wave - b * 112;
        const int jt  = rem >> 4, k64 = rem & 15;
        const int t   = jt * 16 + r16;
        union { signed char c[16]; int4v v; } u;
        if (t < T_STEPS) {
            const float* sp = S + ((size_t)t * 64 + b) * K_DIM + k64 * 64 + quad * 16;
            const float4 s0 = *(const float4*)(sp);
            const float4 s1 = *(const float4*)(sp + 4);
            const float4 s2 = *(const float4*)(sp + 8);
            const float4 s3 = *(const float4*)(sp + 12);
            const float sv[16] = {s0.x,s0.y,s0.z,s0.w, s1.x,s1.y,s1.z,s1.w,
                                  s2.x,s2.y,s2.z,s2.w, s3.x,s3.y,s3.z,s3.w};
#pragma unroll
            for (int e = 0; e < 16; ++e) u.c[e] = (signed char)sv[e];  // exact 0/1
        } else {
#pragma unroll
            for (int e = 0; e < 16; ++e) u.c[e] = 0;                   // t-pad
        }
        // kt-contiguous chunk index: k64*7 + jt
        *(int4v*)(A8 + ((size_t)(b * 112 + k64 * 7 + jt)) * 1024 + lane * 16) = u.v;
    } else {
        const int t2 = wave - 7168;                 // 0..1023
        const int n16 = t2 >> 4, k64 = t2 & 15;
        const int n = n16 * 16 + r16;
        const float* wp = W + (size_t)n * K_DIM + k64 * 64 + quad * 16;
        const float4 w0 = *(const float4*)(wp);
        const float4 w1 = *(const float4*)(wp + 4);
        const float4 w2 = *(const float4*)(wp + 8);
        const float4 w3 = *(const float4*)(wp + 12);
        const float wv[16] = {w0.x,w0.y,w0.z,w0.w, w1.x,w1.y,w1.z,w1.w,
                              w2.x,w2.y,w2.z,w2.w, w3.x,w3.y,w3.z,w3.w};
        union { signed char c[16]; int4v v; } u[4];
#pragma unroll
        for (int e = 0; e < 16; ++e) {
            long long q = llrint((double)wv[e] * 0x1p28);   // |q| < 2^31
#pragma unroll
            for (int p = 0; p < 3; ++p) {
                const int d = (int)(((q + 128) & 255) - 128);  // [-128,127]
                u[p].c[e] = (signed char)d;
                q = (q - d) >> 8;                              // exact
            }
            u[3].c[e] = (signed char)q;                        // |d3| <= ~88
        }
        signed char* base = Bt + (size_t)(n16 * 16 + k64) * 4 * 1024 + lane * 16;
#pragma unroll
        for (int p = 0; p < 4; ++p)
            *(int4v*)(base + (size_t)p * 1024) = u[p].v;
    }
}

// ---- fused GEMM + scan: 2 waves/block, plane-split, 4 waves/SIMD. ----
__global__ __launch_bounds__(128, 4)
void gemm_scan(const signed char* __restrict__ A8,
               const signed char* __restrict__ Bt,
               const float* __restrict__ bias,
               const float* __restrict__ mem0,
               float* __restrict__ out) {
    __shared__ double dulds[T_STEPS * 16];       // 12800 B; aliased i64 for partials
    long long* llds = (long long*)dulds;

    const int bid = blockIdx.x;                  // 0..4095
    const int ng  = bid >> 6;                    // n16 tile 0..63
    const int b   = bid & 63;                    // bid%8 = b%8 -> XCD A-locality

    const int tid  = threadIdx.x;
    const int lane = tid & 63, wid = tid >> 6;   // wid 0/1: planes {2w,2w+1}
    const int quad = lane >> 4, r16 = lane & 15;

    const signed char* abase = A8 + (size_t)b * T_PAD * 1024 + lane * 16;
    const signed char* bbase = Bt + (size_t)ng * 65536 + (size_t)wid * 2048 + lane * 16;

    int4v acc[7][2] = {};

    for (int kt = 0; kt < 16; ++kt) {
        const signed char* ak  = abase + (size_t)kt * 7168;
        const signed char* ak2 = ak + 4096;
        const signed char* bk  = bbase + (size_t)kt * 4096;
        int4v af[7];
        af[0] = *(const int4v*)(ak);
        af[1] = *(const int4v*)(ak + 1024);
        af[2] = *(const int4v*)(ak + 2048);
        af[3] = *(const int4v*)(ak + 3072);
        af[4] = *(const int4v*)(ak2);
        af[5] = *(const int4v*)(ak2 + 1024);
        af[6] = *(const int4v*)(ak2 + 2048);
        const int4v b0 = *(const int4v*)(bk);
        const int4v b1 = *(const int4v*)(bk + 1024);
#pragma unroll
        for (int i = 0; i < 7; ++i)
            acc[i][0] = __builtin_amdgcn_mfma_i32_16x16x64_i8(af[i], b0, acc[i][0], 0, 0, 0);
#pragma unroll
        for (int i = 0; i < 7; ++i)
            acc[i][1] = __builtin_amdgcn_mfma_i32_16x16x64_i8(af[i], b1, acc[i][1], 0, 0, 0);
    }

    // partial Horner: v_w = d(2w) + 256*d(2w+1), exact i64
    if (wid == 1) {
#pragma unroll
        for (int i = 0; i < 7; ++i)
#pragma unroll
            for (int e = 0; e < 4; ++e) {
                const int t = i * 16 + quad * 4 + e;
                if (t < T_STEPS)
                    llds[t * 16 + r16] =
                        (long long)acc[i][1][e] * 256 + (long long)acc[i][0][e];
            }
    }
    __syncthreads();
    if (wid == 0) {
        const double bd = (double)bias[ng * 16 + r16];
#pragma unroll
        for (int i = 0; i < 7; ++i)
#pragma unroll
            for (int e = 0; e < 4; ++e) {
                const int t = i * 16 + quad * 4 + e;
                if (t < T_STEPS) {
                    long long v =
                        (long long)acc[i][1][e] * 256 + (long long)acc[i][0][e];
                    v += llds[t * 16 + r16] << 16;      // + 2^16 * (d2 + 256*d3)
                    dulds[t * 16 + r16] = (double)v * 0x1p-28 + bd;  // exact
                }
            }
    }
    __syncthreads();

    // membrane scan (R16 math verbatim, exact f64 du): wave0 lanes 0-15.
    if (wid == 0 && lane < 16) {
        const int bo = b * 1024 + ng * 16 + lane;
        double m = (double)mem0[bo];
        double cnt = 0.0;
        double d[4];
#pragma unroll
        for (int u = 0; u < 4; ++u) d[u] = dulds[u * 16 + lane];
        for (int g = 0; g < 25; ++g) {
            double dn[4];
            if (g + 1 < 25) {
#pragma unroll
                for (int u = 0; u < 4; ++u) dn[u] = dulds[((g + 1) * 4 + u) * 16 + lane];
            }
#pragma unroll
            for (int u = 0; u < 4; ++u) {
                m += d[u];
                const double s = (m > 15.0) ? 1.0 : 0.0;
                m = fmin(fmax(m, 0.0), 15.0);
                out[(size_t)(g * 4 + u) * BO + bo] = (float)s;
                cnt += s;
                m -= m * s;
            }
            if (g + 1 < 25) {
#pragma unroll
                for (int u = 0; u < 4; ++u) d[u] = dn[u];
            }
        }
        out[(size_t)T_STEPS * BO + bo] = (float)m;
        out[(size_t)(T_STEPS + 1) * BO + bo] = (float)(cnt * 0.01);
    }
}

extern "C" void kernel_launch(void* const* d_in, const int* in_sizes, int n_in,
                              void* d_out, int out_size, void* d_ws, size_t ws_size,
                              hipStream_t stream) {
    const float* spikes = (const float*)d_in[0];  // [100,64,1024]
    const float* mem    = (const float*)d_in[1];  // [64,1024]
    // d_in[2] = hat_spikes: dead in forward
    const float* W      = (const float*)d_in[3];  // [1024,1024]
    const float* b      = (const float*)d_in[4];  // [1024]
    float* out = (float*)d_out;
    signed char* A8 = (signed char*)d_ws + A8_OFF;
    signed char* Bt = (signed char*)d_ws + BT_OFF;

    prepass<<<dim3(2048), 256, 0, stream>>>(spikes, W, A8, Bt);
    gemm_scan<<<dim3(4096), 128, 0, stream>>>(A8, Bt, b, mem, out);
}